// Round 2
// baseline (1077.597 us; speedup 1.0000x reference)
//
#include <hip/hip_runtime.h>
#include <hip/hip_bf16.h>

#define BN 4
#define CC 128
#define SS 4096

using bf16 = __hip_bfloat16;
typedef unsigned int u32;

__device__ __forceinline__ float b2f(bf16 h) { return __bfloat162float(h); }
__device__ __forceinline__ bf16 f2b(float f) { return __float2bfloat16(f); }

__device__ __forceinline__ void unpack8(uint4 v, float* f) {
    u32 u[4] = {v.x, v.y, v.z, v.w};
#pragma unroll
    for (int i = 0; i < 4; ++i) {
        union { u32 b; float ff; } lo, hi;
        lo.b = u[i] << 16;
        hi.b = u[i] & 0xFFFF0000u;
        f[2 * i]     = lo.ff;
        f[2 * i + 1] = hi.ff;
    }
}

// Decide whether float tensors are fp32 (true) or bf16 (false) by inspecting
// the low 16 bits of 16 words of N(0,1) data. bf16 world: low half is a bf16
// sample, exponent in ~[110,140]. fp32 world: low half is mantissa bits,
// exponent uniform in [0,255]. Deterministic & identical for every thread.
__device__ __forceinline__ bool sniff_f32(const void* p) {
    const u32* u = (const u32*)p;
    int bad = 0;
#pragma unroll
    for (int i = 0; i < 16; ++i) {
        u32 w = u[i];
        u32 h = w & 0xFFFFu;
        u32 e = (h >> 7) & 0xFFu;
        if (h != 0u && (e < 100u || e > 140u)) bad++;
    }
    return bad >= 4;
}

__device__ __forceinline__ float ldf(const void* p, size_t i, bool f32) {
    return f32 ? ((const float*)p)[i] : b2f(((const bf16*)p)[i]);
}

struct PArgs {
    const void *x, *w, *b, *sc, *bb, *bm, *bv;
    bf16* out;
};

// K/V projection: out[b][s][o] = ELU(BN(W x))  (position-major bf16)
__global__ __launch_bounds__(256) void projKV_kernel(PArgs aK, PArgs aV, const void* sniffp) {
    const bool f32 = sniff_f32(sniffp);
    PArgs A = blockIdx.y ? aV : aK;
    const int tid = threadIdx.x;
    const int b   = blockIdx.x >> 7;
    const int s0  = (blockIdx.x & 127) * 32;

    __shared__ float xs[CC][32];     // x tile [c][s]
    __shared__ float wl[CC][33];     // W chunk [o][c-sub]

    if (f32) {
#pragma unroll
        for (int i = 0; i < 4; ++i) {
            int vi = tid + i * 256;            // 0..1023
            int r = vi >> 3, cl = (vi & 7) * 4;
            float4 v = *(const float4*)((const float*)A.x + ((size_t)b * CC + r) * SS + s0 + cl);
            xs[r][cl] = v.x; xs[r][cl + 1] = v.y; xs[r][cl + 2] = v.z; xs[r][cl + 3] = v.w;
        }
    } else {
#pragma unroll
        for (int i = 0; i < 2; ++i) {
            int vi = tid + i * 256;            // 0..511
            int r = vi >> 2, cl = (vi & 3) * 8;
            uint4 v = *(const uint4*)((const bf16*)A.x + ((size_t)b * CC + r) * SS + s0 + cl);
            float f[8]; unpack8(v, f);
#pragma unroll
            for (int e = 0; e < 8; ++e) xs[r][cl + e] = f[e];
        }
    }

    const int o = tid & 127, sg = tid >> 7;
    float inv = ldf(A.sc, o, f32) * rsqrtf(ldf(A.bv, o, f32) + 1e-5f);
    float eb  = (ldf(A.b, o, f32) - ldf(A.bm, o, f32)) * inv + ldf(A.bb, o, f32);

    float acc[16];
#pragma unroll
    for (int i = 0; i < 16; ++i) acc[i] = 0.f;

    for (int ch = 0; ch < 4; ++ch) {
        __syncthreads();                       // wl readers of prev chunk done
        if (f32) {
#pragma unroll
            for (int i = 0; i < 4; ++i) {
                int vi = tid + i * 256;
                int r = vi >> 3, cl = (vi & 7) * 4;
                float4 v = *(const float4*)((const float*)A.w + r * CC + ch * 32 + cl);
                wl[r][cl] = v.x; wl[r][cl + 1] = v.y; wl[r][cl + 2] = v.z; wl[r][cl + 3] = v.w;
            }
        } else {
#pragma unroll
            for (int i = 0; i < 2; ++i) {
                int vi = tid + i * 256;
                int r = vi >> 2, cl = (vi & 3) * 8;
                uint4 v = *(const uint4*)((const bf16*)A.w + r * CC + ch * 32 + cl);
                float f[8]; unpack8(v, f);
#pragma unroll
                for (int e = 0; e < 8; ++e) wl[r][cl + e] = f[e];
            }
        }
        __syncthreads();
        for (int c = 0; c < 32; ++c) {
            float wf = wl[o][c] * inv;
            const float* xr = &xs[ch * 32 + c][sg * 16];
#pragma unroll
            for (int si = 0; si < 16; ++si) acc[si] += wf * xr[si];
        }
    }

    bf16* outp = A.out + ((size_t)b * SS + s0 + sg * 16) * CC + o;
#pragma unroll
    for (int si = 0; si < 16; ++si) {
        float y = acc[si] + eb;
        y = (y > 0.f) ? y : (expf(y) - 1.f);
        outp[si * CC] = f2b(y);
    }
}

// Fused Q-projection + flash attention. K/V from ws bf16 [B][S][C].
__global__ __launch_bounds__(256) void attn_kernel(
    const void* __restrict__ xq, const void* __restrict__ qw, const void* __restrict__ qb,
    const void* __restrict__ qsc, const void* __restrict__ qbb, const void* __restrict__ qbm,
    const void* __restrict__ qbv,
    const bf16* __restrict__ Kt, const bf16* __restrict__ Vt,
    const void* __restrict__ xv, const void* __restrict__ gptr, const void* __restrict__ bptr,
    void* __restrict__ outp)
{
    const bool f32 = sniff_f32(xq);
    const int tid = threadIdx.x;
    const int b   = blockIdx.x >> 7;
    const int q0  = (blockIdx.x & 127) * 32;

    __shared__ float Ql[32][132];
    __shared__ float Kl[32][132];
    __shared__ float Vl[32][132];
    __shared__ float Pl[32][36];
    __shared__ float mrow[32], lrow[32], arow[32];

    // ---------- Q projection into Ql (Kl = x scratch, Vl = W scratch) ----------
    float* xsf = &Kl[0][0];                    // [128][32]
    float* wlf = &Vl[0][0];                    // [128][33]
    if (f32) {
#pragma unroll
        for (int i = 0; i < 4; ++i) {
            int vi = tid + i * 256;
            int r = vi >> 3, cl = (vi & 7) * 4;
            float4 v = *(const float4*)((const float*)xq + ((size_t)b * CC + r) * SS + q0 + cl);
            xsf[r * 32 + cl] = v.x; xsf[r * 32 + cl + 1] = v.y;
            xsf[r * 32 + cl + 2] = v.z; xsf[r * 32 + cl + 3] = v.w;
        }
    } else {
#pragma unroll
        for (int i = 0; i < 2; ++i) {
            int vi = tid + i * 256;
            int r = vi >> 2, cl = (vi & 3) * 8;
            uint4 v = *(const uint4*)((const bf16*)xq + ((size_t)b * CC + r) * SS + q0 + cl);
            float f[8]; unpack8(v, f);
#pragma unroll
            for (int e = 0; e < 8; ++e) xsf[r * 32 + cl + e] = f[e];
        }
    }

    const int o = tid & 127, sg = tid >> 7;
    {
        float inv = ldf(qsc, o, f32) * rsqrtf(ldf(qbv, o, f32) + 1e-5f);
        float eb  = (ldf(qb, o, f32) - ldf(qbm, o, f32)) * inv + ldf(qbb, o, f32);
        float qacc[16];
#pragma unroll
        for (int i = 0; i < 16; ++i) qacc[i] = 0.f;
        for (int ch = 0; ch < 4; ++ch) {
            __syncthreads();
            if (f32) {
#pragma unroll
                for (int i = 0; i < 4; ++i) {
                    int vi = tid + i * 256;
                    int r = vi >> 3, cl = (vi & 7) * 4;
                    float4 v = *(const float4*)((const float*)qw + r * CC + ch * 32 + cl);
                    wlf[r * 33 + cl] = v.x; wlf[r * 33 + cl + 1] = v.y;
                    wlf[r * 33 + cl + 2] = v.z; wlf[r * 33 + cl + 3] = v.w;
                }
            } else {
#pragma unroll
                for (int i = 0; i < 2; ++i) {
                    int vi = tid + i * 256;
                    int r = vi >> 2, cl = (vi & 3) * 8;
                    uint4 v = *(const uint4*)((const bf16*)qw + r * CC + ch * 32 + cl);
                    float f[8]; unpack8(v, f);
#pragma unroll
                    for (int e = 0; e < 8; ++e) wlf[r * 33 + cl + e] = f[e];
                }
            }
            __syncthreads();
            for (int c = 0; c < 32; ++c) {
                float wf = wlf[o * 33 + c] * inv;
                const float* xr = &xsf[(ch * 32 + c) * 32 + sg * 16];
#pragma unroll
                for (int si = 0; si < 16; ++si) qacc[si] += wf * xr[si];
            }
        }
#pragma unroll
        for (int si = 0; si < 16; ++si) {
            float y = qacc[si] + eb;
            y = (y > 0.f) ? y : (expf(y) - 1.f);
            Ql[sg * 16 + si][o] = y;
        }
    }
    if (tid < 32) { mrow[tid] = -3.0e38f; lrow[tid] = 0.f; }

    // ---------- flash loop ----------
    const int q = tid >> 3;                    // 0..31
    const int g = tid & 7;                     // 0..7
    float acc[16];
#pragma unroll
    for (int i = 0; i < 16; ++i) acc[i] = 0.f;

    for (int kt = 0; kt < SS / 32; ++kt) {
        const int k0 = kt * 32;
        __syncthreads();                       // prev readers (and Q-proj scratch) done
#pragma unroll
        for (int i = 0; i < 2; ++i) {
            int vi = tid + i * 256;
            int r = vi >> 4, cl = (vi & 15) * 8;
            uint4 v = *(const uint4*)(Kt + ((size_t)b * SS + k0 + r) * CC + cl);
            float f[8]; unpack8(v, f);
#pragma unroll
            for (int e = 0; e < 8; ++e) Kl[r][cl + e] = f[e];
            uint4 v2 = *(const uint4*)(Vt + ((size_t)b * SS + k0 + r) * CC + cl);
            float f2[8]; unpack8(v2, f2);
#pragma unroll
            for (int e = 0; e < 8; ++e) Vl[r][cl + e] = f2[e];
        }
        __syncthreads();
        // phase A: S[q][k], k = g+8j
        float sj[4] = {0.f, 0.f, 0.f, 0.f};
        for (int c4 = 0; c4 < 32; ++c4) {
            float4 qv = *(const float4*)&Ql[q][c4 * 4];
#pragma unroll
            for (int j = 0; j < 4; ++j) {
                float4 kv = *(const float4*)&Kl[g + 8 * j][c4 * 4];
                sj[j] += qv.x * kv.x + qv.y * kv.y + qv.z * kv.z + qv.w * kv.w;
            }
        }
#pragma unroll
        for (int j = 0; j < 4; ++j) Pl[q][g + 8 * j] = sj[j];
        __syncthreads();
        if (tid < 32) {
            int qq = tid;
            float m = mrow[qq];
            float rmax = m;
            for (int k = 0; k < 32; ++k) rmax = fmaxf(rmax, Pl[qq][k]);
            float a = expf(m - rmax);
            float s = 0.f;
            for (int k = 0; k < 32; ++k) {
                float p = expf(Pl[qq][k] - rmax);
                Pl[qq][k] = p;
                s += p;
            }
            mrow[qq] = rmax;
            lrow[qq] = lrow[qq] * a + s;
            arow[qq] = a;
        }
        __syncthreads();
        // phase B: O = O*alpha + P*V
        float al = arow[q];
#pragma unroll
        for (int i = 0; i < 16; ++i) acc[i] *= al;
        for (int k = 0; k < 32; ++k) {
            float p = Pl[q][k];
#pragma unroll
            for (int dd = 0; dd < 4; ++dd) {
                float4 v = *(const float4*)&Vl[k][g * 4 + dd * 32];
                acc[dd * 4 + 0] += p * v.x;
                acc[dd * 4 + 1] += p * v.y;
                acc[dd * 4 + 2] += p * v.z;
                acc[dd * 4 + 3] += p * v.w;
            }
        }
    }
    // epilogue
    float linv = 1.f / lrow[q];
    float gm = ldf(gptr, 0, f32), bt = ldf(bptr, 0, f32);
#pragma unroll
    for (int dd = 0; dd < 4; ++dd)
#pragma unroll
        for (int e = 0; e < 4; ++e) {
            int c = g * 4 + dd * 32 + e;
            size_t idx = ((size_t)b * CC + c) * SS + q0 + q;
            float val = gm * acc[dd * 4 + e] * linv + bt * ldf(xv, idx, f32);
            if (f32) ((float*)outp)[idx] = val;
            else     ((bf16*)outp)[idx]  = f2b(val);
        }
}

extern "C" void kernel_launch(void* const* d_in, const int* in_sizes, int n_in,
                              void* d_out, int out_size, void* d_ws, size_t ws_size,
                              hipStream_t stream) {
    (void)in_sizes; (void)n_in; (void)out_size; (void)ws_size;

    bf16* Kt = (bf16*)d_ws;                          // [B][S][C] bf16 = 4 MB
    bf16* Vt = Kt + (size_t)BN * SS * CC;            // 4 MB

    PArgs ak = { d_in[1], d_in[9],  d_in[10], d_in[11], d_in[12], d_in[13], d_in[14], Kt };
    PArgs av = { d_in[2], d_in[15], d_in[16], d_in[17], d_in[18], d_in[19], d_in[20], Vt };

    hipLaunchKernelGGL(projKV_kernel, dim3(BN * 128, 2), dim3(256), 0, stream, ak, av, d_in[0]);
    hipLaunchKernelGGL(attn_kernel, dim3(BN * 128), dim3(256), 0, stream,
                       d_in[0], d_in[3], d_in[4], d_in[5], d_in[6], d_in[7], d_in[8],
                       Kt, Vt, d_in[2], d_in[21], d_in[22], d_out);
}

// Round 4
// 241.788 us; speedup vs baseline: 4.4568x; 4.4568x over previous
//
#include <hip/hip_runtime.h>
#include <hip/hip_bf16.h>

#define BN 4
#define CC 128
#define SS 4096
#define L2E 1.44269504f

typedef _Float16 f16;
typedef f16 f16x8 __attribute__((ext_vector_type(8)));
typedef float f32x4 __attribute__((ext_vector_type(4)));

// ---------------------------------------------------------------- projections
struct PArgs {
    const float *x, *w, *b, *sc, *bb, *bm, *bv;
    f16* out; int chanMajor;
};

// out = ELU(BN(W x)); Q/K position-major [B][S][C], V channel-major [B][C][S]; f16.
__global__ __launch_bounds__(256) void proj_kernel(PArgs aQ, PArgs aK, PArgs aV) {
    PArgs A = (blockIdx.y == 0) ? aQ : ((blockIdx.y == 1) ? aK : aV);
    const int tid = threadIdx.x;
    const int b   = blockIdx.x >> 7;
    const int s0  = (blockIdx.x & 127) * 32;

    __shared__ float xs[CC][32];   // x tile [c][s]
    __shared__ float wl[CC][33];   // W chunk [o][c_sub]

#pragma unroll
    for (int i = 0; i < 4; ++i) {
        int vi = tid + i * 256;                 // 0..1023
        int r = vi >> 3, cl = (vi & 7) * 4;
        float4 v = *(const float4*)(A.x + ((size_t)b * CC + r) * SS + s0 + cl);
        xs[r][cl] = v.x; xs[r][cl + 1] = v.y; xs[r][cl + 2] = v.z; xs[r][cl + 3] = v.w;
    }

    const int o = tid & 127, sg = tid >> 7;
    float inv = A.sc[o] * rsqrtf(A.bv[o] + 1e-5f);
    float eb  = (A.b[o] - A.bm[o]) * inv + A.bb[o];

    float acc[16];
#pragma unroll
    for (int i = 0; i < 16; ++i) acc[i] = 0.f;

    for (int ch = 0; ch < 4; ++ch) {
        __syncthreads();
#pragma unroll
        for (int i = 0; i < 4; ++i) {
            int vi = tid + i * 256;
            int r = vi >> 3, cl = (vi & 7) * 4;
            float4 v = *(const float4*)(A.w + r * CC + ch * 32 + cl);
            wl[r][cl] = v.x; wl[r][cl + 1] = v.y; wl[r][cl + 2] = v.z; wl[r][cl + 3] = v.w;
        }
        __syncthreads();
        for (int c = 0; c < 32; ++c) {
            float wf = wl[o][c] * inv;
            const float* xr = &xs[ch * 32 + c][sg * 16];
#pragma unroll
            for (int si = 0; si < 16; ++si) acc[si] += wf * xr[si];
        }
    }

    if (A.chanMajor) {
        f16* outp = A.out + ((size_t)b * CC + o) * SS + s0 + sg * 16;
#pragma unroll
        for (int si = 0; si < 16; ++si) {
            float y = acc[si] + eb;
            y = (y > 0.f) ? y : (expf(y) - 1.f);
            outp[si] = (f16)y;
        }
    } else {
        f16* outp = A.out + ((size_t)(b * SS + s0 + sg * 16)) * CC + o;
#pragma unroll
        for (int si = 0; si < 16; ++si) {
            float y = acc[si] + eb;
            y = (y > 0.f) ? y : (expf(y) - 1.f);
            outp[si * CC] = (f16)y;
        }
    }
}

// ---------------------------------------------------------------- attention
// grid 512: bx = b*128 + qt*2 + kh. Q-tile 64 rows; K-range 2048 keys (32 steps of 64).
// Writes unnormalized partial O^T (f16) + m,l (f32) per (b,qt,kh).
__global__ __launch_bounds__(256, 2) void attn_kernel(
    const f16* __restrict__ Qt, const f16* __restrict__ Kt, const f16* __restrict__ Vt,
    f16* __restrict__ Op, float* __restrict__ Ml)
{
    const int tid = threadIdx.x;
    const int bx = blockIdx.x;
    const int b  = bx >> 7;
    const int qt = (bx & 127) >> 1;
    const int kh = bx & 1;
    const int q0 = qt * 64;
    const int kbeg = kh * (SS / 2);

    __shared__ f16 Ql[64][136];
    __shared__ f16 Kl[64][136];
    __shared__ f16 Vl[128][72];
    __shared__ f16 Pl[64][72];
    __shared__ float pm[4][64];
    __shared__ float ps[4][64];

    const int w = tid >> 6, lane = tid & 63;
    const int n = lane & 15, g = lane >> 4;

    // stage Q tile (64 x 128 f16)
#pragma unroll
    for (int i = 0; i < 4; ++i) {
        int vi = tid + i * 256;
        int r = vi >> 4, cl = (vi & 15) * 8;
        *(uint4*)&Ql[r][cl] = *(const uint4*)&Qt[((size_t)b * SS + q0 + r) * CC + cl];
    }
    __syncthreads();
    // preload Q B-frags: lane holds B[k=quad*8+j][n=lane&15] = Q[q=n][c=k]
    f16x8 qf[4][4];
#pragma unroll
    for (int nt = 0; nt < 4; ++nt)
#pragma unroll
        for (int ks = 0; ks < 4; ++ks)
            qf[nt][ks] = *(const f16x8*)&Ql[nt * 16 + n][ks * 32 + g * 8];

    f32x4 oacc[2][4];
#pragma unroll
    for (int mt = 0; mt < 2; ++mt)
#pragma unroll
        for (int nt = 0; nt < 4; ++nt)
            oacc[mt][nt] = (f32x4){0.f, 0.f, 0.f, 0.f};
    float mreg[4], lreg[4];
#pragma unroll
    for (int nt = 0; nt < 4; ++nt) { mreg[nt] = -1e30f; lreg[nt] = 0.f; }

    for (int kt = 0; kt < (SS / 2) / 64; ++kt) {
        const int k0 = kbeg + kt * 64;
        __syncthreads();                       // (1) prev phase-B LDS reads done
#pragma unroll
        for (int i = 0; i < 4; ++i) {
            int vi = tid + i * 256;
            int rk = vi >> 4, ck = (vi & 15) * 8;
            *(uint4*)&Kl[rk][ck] = *(const uint4*)&Kt[((size_t)b * SS + k0 + rk) * CC + ck];
            int rv = vi >> 3, cv = (vi & 7) * 8;
            *(uint4*)&Vl[rv][cv] = *(const uint4*)&Vt[((size_t)b * CC + rv) * SS + k0 + cv];
        }
        __syncthreads();                       // (2) tiles ready

        // phase A: S^T[key][q] = K . Q^T  (wave w owns keys w*16..w*16+15)
        f32x4 sacc[4];
#pragma unroll
        for (int nt = 0; nt < 4; ++nt) sacc[nt] = (f32x4){0.f, 0.f, 0.f, 0.f};
#pragma unroll
        for (int ks = 0; ks < 4; ++ks) {
            f16x8 af = *(const f16x8*)&Kl[w * 16 + n][ks * 32 + g * 8];
#pragma unroll
            for (int nt = 0; nt < 4; ++nt)
                sacc[nt] = __builtin_amdgcn_mfma_f32_16x16x32_f16(af, qf[nt][ks], sacc[nt], 0, 0, 0);
        }

        // wave-partial row max over this wave's 16 keys, per q
        float pmx[4];
#pragma unroll
        for (int nt = 0; nt < 4; ++nt) {
            float v = fmaxf(fmaxf(sacc[nt][0], sacc[nt][1]), fmaxf(sacc[nt][2], sacc[nt][3]));
            v = fmaxf(v, __shfl_xor(v, 16));
            v = fmaxf(v, __shfl_xor(v, 32));
            pmx[nt] = v;
        }
        if (lane < 16) {
#pragma unroll
            for (int nt = 0; nt < 4; ++nt) pm[w][nt * 16 + lane] = pmx[nt];
        }
        __syncthreads();                       // (3) pm ready

        float al[4];
#pragma unroll
        for (int nt = 0; nt < 4; ++nt) {
            int q = nt * 16 + n;
            float mn = fmaxf(fmaxf(pm[0][q], pm[1][q]), fmaxf(pm[2][q], pm[3][q]));
            mn = fmaxf(mn, mreg[nt]);
            al[nt] = exp2f((mreg[nt] - mn) * L2E);
            mreg[nt] = mn;
            float p0 = exp2f((sacc[nt][0] - mn) * L2E);
            float p1 = exp2f((sacc[nt][1] - mn) * L2E);
            float p2 = exp2f((sacc[nt][2] - mn) * L2E);
            float p3 = exp2f((sacc[nt][3] - mn) * L2E);
            float s = p0 + p1 + p2 + p3;
            s += __shfl_xor(s, 16);
            s += __shfl_xor(s, 32);
            if (lane < 16) ps[w][q] = s;       // lane<16 => n==lane
            union { f16 h[4]; uint2 u; } pk;
            pk.h[0] = (f16)p0; pk.h[1] = (f16)p1; pk.h[2] = (f16)p2; pk.h[3] = (f16)p3;
            *(uint2*)&Pl[q][w * 16 + g * 4] = pk.u;   // P[q][key]
        }
        __syncthreads();                       // (4) ps + Pl ready

#pragma unroll
        for (int nt = 0; nt < 4; ++nt) {
            int q = nt * 16 + n;
            lreg[nt] = lreg[nt] * al[nt] + (ps[0][q] + ps[1][q]) + (ps[2][q] + ps[3][q]);
#pragma unroll
            for (int mt = 0; mt < 2; ++mt)
#pragma unroll
                for (int r = 0; r < 4; ++r) oacc[mt][nt][r] *= al[nt];
        }

        // phase B: O^T[c][q] += V . P^T  (wave w owns channels w*32..w*32+31)
#pragma unroll
        for (int ks = 0; ks < 2; ++ks) {
            f16x8 vf[2], pf[4];
#pragma unroll
            for (int mt = 0; mt < 2; ++mt)
                vf[mt] = *(const f16x8*)&Vl[w * 32 + mt * 16 + n][ks * 32 + g * 8];
#pragma unroll
            for (int nt = 0; nt < 4; ++nt)
                pf[nt] = *(const f16x8*)&Pl[nt * 16 + n][ks * 32 + g * 8];
#pragma unroll
            for (int mt = 0; mt < 2; ++mt)
#pragma unroll
                for (int nt = 0; nt < 4; ++nt)
                    oacc[mt][nt] = __builtin_amdgcn_mfma_f32_16x16x32_f16(vf[mt], pf[nt], oacc[mt][nt], 0, 0, 0);
        }
    }

    // epilogue: partial O^T (f16) + m,l
    f16* OpW = Op + ((size_t)(b * 64 + qt) * 2 + kh) * 8192;
#pragma unroll
    for (int mt = 0; mt < 2; ++mt)
#pragma unroll
        for (int nt = 0; nt < 4; ++nt)
#pragma unroll
            for (int r = 0; r < 4; ++r) {
                int c = w * 32 + mt * 16 + g * 4 + r;
                int q = nt * 16 + n;
                OpW[c * 64 + q] = (f16)oacc[mt][nt][r];
            }
    if (w == 0 && lane < 16) {
        float* MlW = Ml + (size_t)(b * 64 + qt) * 256 + kh * 128;
#pragma unroll
        for (int nt = 0; nt < 4; ++nt) {
            int q = nt * 16 + lane;
            MlW[q]      = mreg[nt];
            MlW[64 + q] = lreg[nt];
        }
    }
}

// ---------------------------------------------------------------- merge
__global__ __launch_bounds__(256) void merge_kernel(
    const f16* __restrict__ Op, const float* __restrict__ Ml,
    const float* __restrict__ xv, const float* __restrict__ gp, const float* __restrict__ bp,
    float* __restrict__ out)
{
    const int bq = blockIdx.x;                 // b*64 + qt
    const int b = bq >> 6, qt = bq & 63;
    const int t = threadIdx.x;
    const int q = t & 63, cg = t >> 6;

    const float* ml = Ml + (size_t)bq * 256;
    float m1 = ml[q], l1 = ml[64 + q], m2 = ml[128 + q], l2 = ml[192 + q];
    float m = fmaxf(m1, m2);
    float w1 = exp2f((m1 - m) * L2E), w2 = exp2f((m2 - m) * L2E);
    float inv = 1.f / (w1 * l1 + w2 * l2);
    float gm = gp[0], bb = bp[0];

    const f16* O1 = Op + (size_t)bq * 2 * 8192;
    const f16* O2 = O1 + 8192;
#pragma unroll 4
    for (int i = 0; i < 32; ++i) {
        int c = cg * 32 + i;
        float o = (w1 * (float)O1[c * 64 + q] + w2 * (float)O2[c * 64 + q]) * inv;
        size_t idx = ((size_t)(b * CC + c)) * SS + qt * 64 + q;
        out[idx] = gm * o + bb * xv[idx];
    }
}

// ---------------------------------------------------------------- launcher
extern "C" void kernel_launch(void* const* d_in, const int* in_sizes, int n_in,
                              void* d_out, int out_size, void* d_ws, size_t ws_size,
                              hipStream_t stream) {
    (void)in_sizes; (void)n_in; (void)out_size; (void)ws_size;

    const size_t TEN = (size_t)BN * SS * CC;         // 2,097,152 elems
    f16* Qt = (f16*)d_ws;                            // 4 MB
    f16* Kt = Qt + TEN;                              // 4 MB
    f16* Vt = Kt + TEN;                              // 4 MB (channel-major)
    f16* Op = Vt + TEN;                              // 512 * 8192 f16 = 8 MB
    float* Ml = (float*)(Op + (size_t)512 * 8192);   // 512 KB

    PArgs aq = { (const float*)d_in[0], (const float*)d_in[3],  (const float*)d_in[4],
                 (const float*)d_in[5], (const float*)d_in[6],  (const float*)d_in[7],
                 (const float*)d_in[8],  Qt, 0 };
    PArgs ak = { (const float*)d_in[1], (const float*)d_in[9],  (const float*)d_in[10],
                 (const float*)d_in[11], (const float*)d_in[12], (const float*)d_in[13],
                 (const float*)d_in[14], Kt, 0 };
    PArgs av = { (const float*)d_in[2], (const float*)d_in[15], (const float*)d_in[16],
                 (const float*)d_in[17], (const float*)d_in[18], (const float*)d_in[19],
                 (const float*)d_in[20], Vt, 1 };

    hipLaunchKernelGGL(proj_kernel, dim3(BN * 128, 3), dim3(256), 0, stream, aq, ak, av);
    hipLaunchKernelGGL(attn_kernel, dim3(512), dim3(256), 0, stream, Qt, Kt, Vt, Op, Ml);
    hipLaunchKernelGGL(merge_kernel, dim3(256), dim3(256), 0, stream,
                       Op, Ml, (const float*)d_in[2], (const float*)d_in[21],
                       (const float*)d_in[22], (float*)d_out);
}